// Round 13
// baseline (229.876 us; speedup 1.0000x reference)
//
#include <hip/hip_runtime.h>
#include <hip/hip_fp16.h>
#include <math.h>

// CrossFeatureAffinityPooling on gfx950 — R19
// R18 (226.5µs; atomic fix -36µs confirmed) + k_qkgemm residency push:
// 16-row blocks, grid.x 256 -> 2048 blocks = 8/CU = 32 waves/CU (full).
// All 4 waves share one 16-row A-fragment (dup loads hit L1; HBM X traffic
// unchanged — R13's failure mode avoided); each wave owns an osub quarter.
// Stores: qT 8KB contig, kT 512B runs (unchanged); Uh 64B->32B runs (~+2µs,
// accepted). Free rider: NSLOT 16->32. k_attn identical to R18 (saturated).

typedef _Float16 v8h __attribute__((ext_vector_type(8)));
typedef float    v4f __attribute__((ext_vector_type(4)));

#define NB 4
#define NC 256
#define NS 4096
#define NG 32
#define GEPS 1e-5f
#define NSPLIT 3
#define NSLOT 32               // statacc contention-spreading slots
#define KSTRIDE 272            // halves per K-tile row (256 data + 16 pad)
#define KTILE   8704           // halves per 32-row K tile (17408 B = 17 KiB)
#define PSTRIDE 40             // halves per P row (32 data + 8 pad)
#define LOG2E   1.44269504f

// raw barrier: LDS-visibility only (lgkm drain), vmem stays in flight
#define ASYNC_BARRIER() asm volatile("s_waitcnt lgkmcnt(0)\n\ts_barrier" ::: "memory")

// DPP rotation-reduce within each 16-lane row (the l15 domain of MFMA quads)
template <int CTRL>
__device__ __forceinline__ float dpp_rot(float x) {
    int r = __builtin_amdgcn_update_dpp(__float_as_int(x), __float_as_int(x),
                                        CTRL, 0xF, 0xF, false);
    return __int_as_float(r);
}
__device__ __forceinline__ float row_max16(float x) {
    x = fmaxf(x, dpp_rot<0x128>(x));
    x = fmaxf(x, dpp_rot<0x124>(x));
    x = fmaxf(x, dpp_rot<0x122>(x));
    x = fmaxf(x, dpp_rot<0x121>(x));
    return x;
}
__device__ __forceinline__ float row_sum16(float x) {
    x = x + dpp_rot<0x128>(x);
    x = x + dpp_rot<0x124>(x);
    x = x + dpp_rot<0x122>(x);
    x = x + dpp_rot<0x121>(x);
    return x;
}

// ---------------- K0: convert weights into MFMA-frag order + zero statacc ---
__global__ __launch_bounds__(256) void k_convert(const float* __restrict__ Wh,
    const float* __restrict__ Wu, _Float16* __restrict__ Wh16,
    _Float16* __restrict__ Wu16, float* __restrict__ statacc)
{
    if (blockIdx.x < NSLOT)                     // NSLOT*NB*NG*2 = 8192 floats
        statacc[blockIdx.x * 256 + threadIdx.x] = 0.f;
    const int i = blockIdx.x * 256 + threadIdx.x;      // i < NC*NC
    const int o = i >> 8, c = i & 255;
    const int idx = ((((o >> 4) * 8 + (c >> 5)) * 4 + ((c >> 3) & 3)) * 16
                     + (o & 15)) * 8 + (c & 7);
    Wh16[idx] = (_Float16)Wh[i];
    Wu16[idx] = (_Float16)Wu[i];
}

// ---------------- K1: q^T / k^T GEMM (+ fused Uh materialization) ----------
// 16-row blocks: all 4 waves share one A-fragment (L1 reuse), each wave owns
// an osub quarter. 2048 blocks = 8/CU = full wave residency.
__global__ __launch_bounds__(256) void k_qkgemm(const float* __restrict__ Hand,
    const float* __restrict__ U, const _Float16* __restrict__ Wh16,
    const _Float16* __restrict__ Wu16, const float* __restrict__ WHb,
    const float* __restrict__ WUb, _Float16* __restrict__ qT,
    _Float16* __restrict__ kTsw, _Float16* __restrict__ Uh)
{
    const int nt4 = blockIdx.x, b = blockIdx.y, z = blockIdx.z;
    const float*    X    = z ? U    : Hand;
    const _Float16* W    = z ? Wu16 : Wh16;
    const float*    bias = z ? WUb  : WHb;

    __shared__ __align__(16) _Float16 S[16 * 256];   // 8 KiB staging

    const int tid = threadIdx.x, w = tid >> 6, lane = tid & 63;
    const int q4 = lane >> 4, l15 = lane & 15;
    const int n = nt4 * 16 + l15;

    const float* Xcol = X + (size_t)b * NC * NS + n;
    v8h A[8];
#pragma unroll
    for (int kc = 0; kc < 8; ++kc) {
        const int c0 = kc * 32 + q4 * 8;
        v8h a;
#pragma unroll
        for (int j = 0; j < 8; ++j) a[j] = (_Float16)Xcol[(size_t)(c0 + j) * NS];
        A[kc] = a;
    }

    // fused: z=1 wave 0 stages U^T[n][c] as S[c][l15], then cooperative write
    // Uh[b][c][n] in 32B runs (2 x 16B chunks per channel).
    if (z == 1) {
        if (w == 0) {
#pragma unroll
            for (int kc = 0; kc < 8; ++kc) {
                const int c0 = kc * 32 + q4 * 8;
#pragma unroll
                for (int j = 0; j < 8; ++j)
                    S[(c0 + j) * 16 + l15] = A[kc][j];
            }
        }
        ASYNC_BARRIER();
        {
            _Float16* ub = Uh + (size_t)b * NC * NS + nt4 * 16;
#pragma unroll
            for (int i = 0; i < 2; ++i) {
                const int idx16 = tid + i * 256;         // 512 x 16B chunks
                const int c = idx16 >> 1, part = idx16 & 1;
                const v8h v = *(const v8h*)(S + idx16 * 8);
                __builtin_nontemporal_store(v, (v8h*)(ub + (size_t)c * NS + part * 8));
            }
        }
        ASYNC_BARRIER();   // S reads retired before the output staging below
    }

#pragma unroll
    for (int os2 = 0; os2 < 4; ++os2) {
        const int osub = w * 4 + os2;
        const int o = osub * 16 + l15;
        v4f acc = {0.f, 0.f, 0.f, 0.f};
#pragma unroll
        for (int kc = 0; kc < 8; ++kc) {
            // pre-swizzled W: wave reads 1 KB contiguous, lane-coalesced b128
            const v8h bf = *(const v8h*)(W + ((size_t)(osub * 8 + kc) * 64 + lane) * 8);
            acc = __builtin_amdgcn_mfma_f32_16x16x32_f16(A[kc], bf, acc, 0, 0, 0);
        }
        const float bv = bias[o];
        // stage rows in S[16][256]; q scaled by log2e (base-2 softmax)
#pragma unroll
        for (int r = 0; r < 4; ++r) {
            const float v = z == 0 ? (acc[r] + bv) * LOG2E : (acc[r] + bv);
            S[(q4 * 4 + r) * 256 + o] = (_Float16)v;
        }
    }
    ASYNC_BARRIER();

    if (z == 0) {
        // qT rows nt4*16..+16 are one contiguous 8 KB block
        _Float16* dstQ = qT + ((size_t)b * NS + nt4 * 16) * NC;
#pragma unroll
        for (int i = 0; i < 2; ++i) {
            const int idx16 = tid + i * 256;
            const v8h v = *(const v8h*)(S + idx16 * 8);
            __builtin_nontemporal_store(v, (v8h*)(dstQ + (size_t)idx16 * 8));
        }
    } else {
        // kTsw: rows (nt4&1)*16.. of tile nt4>>1; 512B runs per row
        _Float16* kb = kTsw + (size_t)b * 128 * KTILE;
#pragma unroll
        for (int i = 0; i < 2; ++i) {
            const int idx16 = tid + i * 256;
            const int row = idx16 >> 5, col = (idx16 & 31) * 8;
            const v8h v = *(const v8h*)(S + idx16 * 8);
            __builtin_nontemporal_store(v,
                (v8h*)(kb + (size_t)(nt4 >> 1) * KTILE
                       + ((nt4 & 1) * 16 + row) * KSTRIDE + col));
        }
    }
}

// ---------------- K2: flash attention partial, pipelined single-barrier ----
template <int NSPL>
__global__ __launch_bounds__(256, 3) void k_attn(const _Float16* __restrict__ qT,
    const _Float16* __restrict__ kTsw, const _Float16* __restrict__ Uh,
    _Float16* __restrict__ Ppart, float* __restrict__ mstat, float* __restrict__ lstat)
{
    const int b  = blockIdx.x;
    const int nt = blockIdx.y;
    const int s  = blockIdx.z;
    const int t0 = (s * 128) / NSPL;
    const int t1 = ((s + 1) * 128) / NSPL;

    __shared__ __align__(16) _Float16 Klds[2][KTILE];        // 2 x 17 KiB, padded
    __shared__ __align__(16) _Float16 Plds[2][64 * PSTRIDE]; // 2 x 5 KiB, padded
    __shared__ __align__(16) float alphaS[2][64];

    const int tid = threadIdx.x, w = tid >> 6, lane = tid & 63;
    const int q4 = lane >> 4, l15 = lane & 15;

    const _Float16* kTb = kTsw + (size_t)b * 128 * KTILE;
    const _Float16* Uhb = Uh + (size_t)b * NC * NS;

    v8h Q[8];
    v8h Ur[4];
    v4f O[4][4];
    v4f sv[2];
    float mi[4] = {-INFINITY, -INFINITY, -INFINITY, -INFINITY};
    float li[4] = {0.f, 0.f, 0.f, 0.f};   // lane-local partial (own cols only)

    // DMA one 32-row K tile (17 chunks of 1 KiB; 5 per wave via (w*5+j)%17,
    // chunks 0..2 double-copied -> uniform 5 outstanding per wave)
    auto DMA = [&](int t, int kb) {
        const _Float16* src = kTb + (size_t)t * KTILE;
#pragma unroll
        for (int j = 0; j < 5; ++j) {
            const int ch = (w * 5 + j) % 17;
            __builtin_amdgcn_global_load_lds(
                (const __attribute__((address_space(1))) void*)(src + ch * 512 + lane * 8),
                (__attribute__((address_space(3))) void*)(&Klds[kb][ch * 512]), 16, 0, 0);
        }
    };
    // QK^T from Klds[kb]: 16 n-rows x 32 m per wave
    auto QK = [&](int kb) {
        sv[0] = (v4f){0.f, 0.f, 0.f, 0.f};
        sv[1] = (v4f){0.f, 0.f, 0.f, 0.f};
#pragma unroll
        for (int kc = 0; kc < 8; ++kc) {
#pragma unroll
            for (int ms = 0; ms < 2; ++ms) {
                const v8h kf = *(const v8h*)(&Klds[kb][(ms * 16 + l15) * KSTRIDE
                                             + (kc * 4 + q4) * 8]);
                sv[ms] = __builtin_amdgcn_mfma_f32_16x16x32_f16(Q[kc], kf, sv[ms], 0, 0, 0);
            }
        }
    };
    // online softmax (base-2) on sv, write P/alpha into buffer pb
    auto SMAX = [&](int pb) {
        float al[4];
#pragma unroll
        for (int r = 0; r < 4; ++r) {
            const float tm = row_max16(fmaxf(sv[0][r], sv[1][r]));
            const float mn = fmaxf(mi[r], tm);
            al[r] = __builtin_amdgcn_exp2f(mi[r] - mn);
            mi[r] = mn;
            const float p0 = __builtin_amdgcn_exp2f(sv[0][r] - mn);
            const float p1 = __builtin_amdgcn_exp2f(sv[1][r] - mn);
            sv[0][r] = p0; sv[1][r] = p1;
            li[r] = li[r] * al[r] + p0 + p1;
        }
        if (l15 == 0) {
#pragma unroll
            for (int r = 0; r < 4; ++r) alphaS[pb][w * 16 + q4 * 4 + r] = al[r];
        }
#pragma unroll
        for (int ms = 0; ms < 2; ++ms)
#pragma unroll
            for (int r = 0; r < 4; ++r) {
                const int row = w * 16 + q4 * 4 + r;
                Plds[pb][row * PSTRIDE + ms * 16 + l15] = (_Float16)sv[ms][r];
            }
    };
    // O = O*alpha + P x U, reading buffer pb (written LAST iteration)
    auto PV = [&](int pb) {
#pragma unroll
        for (int is = 0; is < 4; ++is) {
            const float4 av = *(const float4*)&alphaS[pb][is * 16 + q4 * 4];
            const v4f aa = {av.x, av.y, av.z, av.w};
#pragma unroll
            for (int js = 0; js < 4; ++js) O[is][js] *= aa;
        }
#pragma unroll
        for (int is = 0; is < 4; ++is) {
            const v8h Pf = *(const v8h*)(&Plds[pb][(is * 16 + l15) * PSTRIDE + q4 * 8]);
#pragma unroll
            for (int js = 0; js < 4; ++js)
                O[is][js] = __builtin_amdgcn_mfma_f32_16x16x32_f16(Pf, Ur[js], O[is][js], 0, 0, 0);
        }
    };
    auto ULOAD = [&](int t) {
#pragma unroll
        for (int js = 0; js < 4; ++js)
            Ur[js] = *(const v8h*)(Uhb + (size_t)(w * 64 + js * 16 + l15) * NS
                                   + t * 32 + q4 * 8);
    };

#pragma unroll
    for (int i = 0; i < 4; ++i)
#pragma unroll
        for (int j = 0; j < 4; ++j) O[i][j] = (v4f){0.f, 0.f, 0.f, 0.f};

    // ---- prologue: DMA K[t0]; Q; QK(t0); DMA K[t0+1]; softmax(t0); U[t0] ----
    DMA(t0, 0);
    asm volatile("" ::: "memory");
    {
        const _Float16* qrow = qT + ((size_t)b * NS + nt * 64 + w * 16 + l15) * NC;
#pragma unroll
        for (int kc = 0; kc < 8; ++kc) Q[kc] = *(const v8h*)(qrow + kc * 32 + q4 * 8);
    }
    asm volatile("" ::: "memory");
    asm volatile("s_waitcnt vmcnt(8)" ::: "memory");   // retire DMA(t0), keep Q(8)
    ASYNC_BARRIER();                                    // K[t0] resident
    QK(0);
    DMA((t0 + 1 < t1) ? t0 + 1 : t0, 1);
    asm volatile("" ::: "memory");
    SMAX(0);
    ULOAD(t0);

    // ---- main loop: one barrier per tile; PV(t-1) overlaps softmax(t) ----
    for (int t = t0 + 1; t < t1; ++t) {
        const int e = (t - t0) & 1;
        // outstanding: DMA(t)=5 oldest, U(t-1)=4 -> retire DMA(t) only
        asm volatile("s_waitcnt vmcnt(4)" ::: "memory");
        ASYNC_BARRIER();   // K[t] resident; P/alpha[e^1] visible; p^1-reads retired
        QK(e);
        DMA((t + 1 < t1) ? t + 1 : t0, e ^ 1);          // post-barrier issue (safe)
        asm volatile("" ::: "memory");
        PV(e ^ 1);         // MFMA pipe: finish tile t-1
        SMAX(e);           // VALU pipe: softmax tile t (other blocks' MFMA overlaps)
        ULOAD(t);          // U[t] for PV(t) next iter (old Ur just consumed)
    }

    // ---- epilogue: finish PV(t1-1); drain wrap DMA ----
    asm volatile("s_waitcnt vmcnt(0)" ::: "memory");
    ASYNC_BARRIER();       // Plds/alphaS of last tile visible
    PV((t1 - 1 - t0) & 1);

    // reduce li across the quad-row, write stats + raw O
#pragma unroll
    for (int r = 0; r < 4; ++r) li[r] = row_sum16(li[r]);
    if (l15 == 0) {
#pragma unroll
        for (int r = 0; r < 4; ++r) {
            const int n = nt * 64 + w * 16 + q4 * 4 + r;
            mstat[(size_t)(s * NB + b) * NS + n] = mi[r];
            lstat[(size_t)(s * NB + b) * NS + n] = li[r];
        }
    }
#pragma unroll
    for (int is = 0; is < 4; ++is)
#pragma unroll
        for (int js = 0; js < 4; ++js)
#pragma unroll
            for (int r = 0; r < 4; ++r) {
                _Float16* dst = Ppart + ((size_t)(s * NB + b) * NS + nt * 64 + is * 16
                                         + q4 * 4 + r) * NC + w * 64 + js * 16 + l15;
                __builtin_nontemporal_store((_Float16)O[is][js][r], dst);
            }
}

// ---------------- K3: merge NSPL partials -> fp32 Opre + fused GN sums -----
// exp2 domain; statacc is NSLOT-slot [slot][b][g][2] to spread atomic contention.
template <int NSPL>
__global__ __launch_bounds__(256) void k_merge(const _Float16* __restrict__ Pp,
    const float* __restrict__ mstat, const float* __restrict__ lstat,
    float* __restrict__ Opre, float* __restrict__ statacc)
{
    const int b = blockIdx.y, tid = threadIdx.x;
    const int n = blockIdx.x * 8 + (tid >> 5);
    const int slot = blockIdx.x & (NSLOT - 1);
    const int c0 = (tid & 31) * 8;            // == group (tid&31) exactly
    const size_t nb = (size_t)b * NS + n;
    const size_t SP = (size_t)NB * NS;

    float m[NSPL], l[NSPL];
#pragma unroll
    for (int sp = 0; sp < NSPL; ++sp) {
        m[sp] = mstat[sp * SP + nb];
        l[sp] = lstat[sp * SP + nb];
    }
    float M = m[0];
#pragma unroll
    for (int sp = 1; sp < NSPL; ++sp) M = fmaxf(M, m[sp]);
    float denom = 0.f, wgt[NSPL];
#pragma unroll
    for (int sp = 0; sp < NSPL; ++sp) {
        wgt[sp] = exp2f(m[sp] - M);
        denom += wgt[sp] * l[sp];
    }
    const float inv = 1.f / denom;

    const size_t base = nb * NC + c0;
    float v[8] = {0.f, 0.f, 0.f, 0.f, 0.f, 0.f, 0.f, 0.f};
#pragma unroll
    for (int sp = 0; sp < NSPL; ++sp) {
        const float ws = wgt[sp] * inv;
        const v8h pv = *(const v8h*)(Pp + (size_t)sp * SP * NC + base);
#pragma unroll
        for (int j = 0; j < 8; ++j) v[j] += ws * (float)pv[j];
    }
    float s1 = 0.f, s2 = 0.f;
#pragma unroll
    for (int j = 0; j < 8; ++j) { s1 += v[j]; s2 += v[j] * v[j]; }
    *(float4*)(Opre + base)     = make_float4(v[0], v[1], v[2], v[3]);
    *(float4*)(Opre + base + 4) = make_float4(v[4], v[5], v[6], v[7]);

    __shared__ float r1[256], r2[256];
    r1[tid] = s1; r2[tid] = s2;
    __syncthreads();
    if (tid < 32) {
        float a = 0.f, q = 0.f;
#pragma unroll
        for (int k = 0; k < 8; ++k) { a += r1[tid + 32 * k]; q += r2[tid + 32 * k]; }
        atomicAdd(&statacc[(((size_t)slot * NB + b) * NG + tid) * 2 + 0], a);
        atomicAdd(&statacc[(((size_t)slot * NB + b) * NG + tid) * 2 + 1], q);
    }
}

// ---------------- K4: apply GN + residual, [b][n][c] -> [b][c][n] ----------
__global__ __launch_bounds__(256) void k_gnapply(const float* __restrict__ Opre,
    const float* __restrict__ Hand, const float* __restrict__ gnw,
    const float* __restrict__ gnb, const float* __restrict__ statacc,
    float* __restrict__ out)
{
    const int nt = blockIdx.x, ct = blockIdx.y, b = blockIdx.z;
    __shared__ float buf[64 * 65];
    __shared__ float gstat[16];   // 8 local groups x {sum, sumsq}
    const int tid = threadIdx.x;
    // pre-reduce the NSLOT statacc slots for this block's 8 channel-groups
    if (tid < 16) {
        const int gl = tid >> 1, comp = tid & 1;
        const int g = ct * 8 + gl;
        float s = 0.f;
#pragma unroll
        for (int sl = 0; sl < NSLOT; ++sl)
            s += statacc[(((size_t)sl * NB + b) * NG + g) * 2 + comp];
        gstat[gl * 2 + comp] = s;
    }
    {
        const int nr = tid >> 4, c4 = (tid & 15) * 4;
#pragma unroll
        for (int k = 0; k < 4; ++k) {
            const int n = nr + 16 * k;
            const float4 v = *(const float4*)(Opre + ((size_t)b * NS + nt * 64 + n) * NC
                                              + ct * 64 + c4);
            buf[n * 65 + c4 + 0] = v.x; buf[n * 65 + c4 + 1] = v.y;
            buf[n * 65 + c4 + 2] = v.z; buf[n * 65 + c4 + 3] = v.w;
        }
    }
    __syncthreads();
    const int nw = tid & 63, c0 = tid >> 6;
#pragma unroll
    for (int k = 0; k < 16; ++k) {
        const int cl = c0 + 4 * k;
        const int c  = ct * 64 + cl;
        const int gl = cl >> 3;
        const float s1   = gstat[gl * 2 + 0];
        const float s2   = gstat[gl * 2 + 1];
        const float mean = s1 * (1.f / 32768.f);
        const float var  = s2 * (1.f / 32768.f) - mean * mean;
        const float rstd = rsqrtf(var + GEPS);
        const size_t oidx = ((size_t)b * NC + c) * NS + nt * 64 + nw;
        out[oidx] = (buf[nw * 65 + cl] - mean) * rstd * gnw[c] + gnb[c] + Hand[oidx];
    }
}

extern "C" void kernel_launch(void* const* d_in, const int* in_sizes, int n_in,
                              void* d_out, int out_size, void* d_ws, size_t ws_size,
                              hipStream_t stream)
{
    const float* Hand = (const float*)d_in[0];
    const float* U    = (const float*)d_in[1];
    const float* WHw  = (const float*)d_in[2];
    const float* WHb  = (const float*)d_in[3];
    const float* WUw  = (const float*)d_in[4];
    const float* WUb  = (const float*)d_in[5];
    const float* gnw  = (const float*)d_in[6];
    const float* gnb  = (const float*)d_in[7];
    float* out = (float*)d_out;

    // workspace (~49.2 MiB; ws >= 60MB established in R9's nsplit=4 run).
    // Opre(fp32,16Mi) ALIASES qT + kTsw head (dead post-attn).
    char* ws = (char*)d_ws;
    _Float16* qT     = (_Float16*)(ws);                  //  8 MiB   [b][n][c]
    _Float16* kTsw   = (_Float16*)(ws + 8388608);        //  8.5 MiB padded 32-row tiles
    _Float16* Uh     = (_Float16*)(ws + 17301504);       //  8 MiB   [b][c][m]
    _Float16* Wh16   = (_Float16*)(ws + 25690112);       //  128 KiB (frag-order)
    _Float16* Wu16   = (_Float16*)(ws + 25821184);       //  128 KiB (frag-order)
    float*    mstat  = (float*)(ws + 25952256);          //  192 KiB [3][b][n]
    float*    lstat  = (float*)(ws + 26148864);          //  192 KiB
    float*    statacc= (float*)(ws + 26345472);          //  32 KiB [slot][b][g][2]
    _Float16* Ppart  = (_Float16*)(ws + 26378240);       //  24 MiB [3][b][n][c]
    float*    Opre   = (float*)(ws);                     //  16 MiB alias

    k_convert<<<dim3((NC * NC) / 256), 256, 0, stream>>>(WHw, WUw, Wh16, Wu16, statacc);
    k_qkgemm <<<dim3(256, NB, 2), 256, 0, stream>>>(Hand, U, Wh16, Wu16, WHb, WUb, qT, kTsw, Uh);
    k_attn<NSPLIT>   <<<dim3(NB, 64, NSPLIT), 256, 0, stream>>>(qT, kTsw, Uh, Ppart, mstat, lstat);
    k_merge<NSPLIT>  <<<dim3(NS / 8, NB), 256, 0, stream>>>(Ppart, mstat, lstat, Opre, statacc);
    k_gnapply<<<dim3(64, 4, NB), 256, 0, stream>>>(Opre, Hand, gnw, gnb, statacc, out);
}

// Round 14
// 225.665 us; speedup vs baseline: 1.0187x; 1.0187x over previous
//
#include <hip/hip_runtime.h>
#include <hip/hip_fp16.h>
#include <math.h>

// CrossFeatureAffinityPooling on gfx950 — R20
// R19 post-mortem: 16-row qkgemm split regressed (−3.4µs: 4x W re-reads, 32B Uh
// runs, 2x launches) -> k_qkgemm + NSLOT reverted to R18 (226.5µs best).
// One new cut: Opre fp32 -> fp16 (merged O already fp16-rounded via Ppart;
// extra rounding ≤5e-4). Halves merge-write + gnapply-read (16MB less HBM);
// Opre now fits inside dead qT region (8MB). gnapply stages via v8h loads.

typedef _Float16 v8h __attribute__((ext_vector_type(8)));
typedef float    v4f __attribute__((ext_vector_type(4)));

#define NB 4
#define NC 256
#define NS 4096
#define NG 32
#define GEPS 1e-5f
#define NSPLIT 3
#define NSLOT 16               // statacc contention-spreading slots
#define KSTRIDE 272            // halves per K-tile row (256 data + 16 pad)
#define KTILE   8704           // halves per 32-row K tile (17408 B = 17 KiB)
#define PSTRIDE 40             // halves per P row (32 data + 8 pad)
#define LOG2E   1.44269504f

// raw barrier: LDS-visibility only (lgkm drain), vmem stays in flight
#define ASYNC_BARRIER() asm volatile("s_waitcnt lgkmcnt(0)\n\ts_barrier" ::: "memory")

// DPP rotation-reduce within each 16-lane row (the l15 domain of MFMA quads)
template <int CTRL>
__device__ __forceinline__ float dpp_rot(float x) {
    int r = __builtin_amdgcn_update_dpp(__float_as_int(x), __float_as_int(x),
                                        CTRL, 0xF, 0xF, false);
    return __int_as_float(r);
}
__device__ __forceinline__ float row_max16(float x) {
    x = fmaxf(x, dpp_rot<0x128>(x));
    x = fmaxf(x, dpp_rot<0x124>(x));
    x = fmaxf(x, dpp_rot<0x122>(x));
    x = fmaxf(x, dpp_rot<0x121>(x));
    return x;
}
__device__ __forceinline__ float row_sum16(float x) {
    x = x + dpp_rot<0x128>(x);
    x = x + dpp_rot<0x124>(x);
    x = x + dpp_rot<0x122>(x);
    x = x + dpp_rot<0x121>(x);
    return x;
}

// ---------------- K0: convert weights into MFMA-frag order + zero statacc ---
__global__ __launch_bounds__(256) void k_convert(const float* __restrict__ Wh,
    const float* __restrict__ Wu, _Float16* __restrict__ Wh16,
    _Float16* __restrict__ Wu16, float* __restrict__ statacc)
{
    if (blockIdx.x < NSLOT)                     // NSLOT*NB*NG*2 = 4096 floats
        statacc[blockIdx.x * 256 + threadIdx.x] = 0.f;
    const int i = blockIdx.x * 256 + threadIdx.x;      // i < NC*NC
    const int o = i >> 8, c = i & 255;
    const int idx = ((((o >> 4) * 8 + (c >> 5)) * 4 + ((c >> 3) & 3)) * 16
                     + (o & 15)) * 8 + (c & 7);
    Wh16[idx] = (_Float16)Wh[i];
    Wu16[idx] = (_Float16)Wu[i];
}

// ---------------- K1: q^T / k^T GEMM (+ fused Uh materialization) ----------
// n-split: 32 rows/block, wave pairs share A (L1 reuse) and split osub range.
__global__ __launch_bounds__(256) void k_qkgemm(const float* __restrict__ Hand,
    const float* __restrict__ U, const _Float16* __restrict__ Wh16,
    const _Float16* __restrict__ Wu16, const float* __restrict__ WHb,
    const float* __restrict__ WUb, _Float16* __restrict__ qT,
    _Float16* __restrict__ kTsw, _Float16* __restrict__ Uh)
{
    const int nt2 = blockIdx.x, b = blockIdx.y, z = blockIdx.z;
    const float*    X    = z ? U    : Hand;
    const _Float16* W    = z ? Wu16 : Wh16;
    const float*    bias = z ? WUb  : WHb;

    __shared__ __align__(16) _Float16 S[32 * 256];   // 16 KiB staging

    const int tid = threadIdx.x, w = tid >> 6, lane = tid & 63;
    const int q4 = lane >> 4, l15 = lane & 15;
    const int g = w >> 1;           // row group (0/1): waves {0,1} / {2,3}
    const int h = w & 1;            // osub half (0/1)
    const int nloc = g * 16 + l15;  // local row 0..31
    const int n = nt2 * 32 + nloc;

    const float* Xcol = X + (size_t)b * NC * NS + n;
    v8h A[8];
#pragma unroll
    for (int kc = 0; kc < 8; ++kc) {
        const int c0 = kc * 32 + q4 * 8;
        v8h a;
#pragma unroll
        for (int j = 0; j < 8; ++j) a[j] = (_Float16)Xcol[(size_t)(c0 + j) * NS];
        A[kc] = a;
    }

    // fused: z=1 blocks stage U^T[n][c] frags as S[c][nloc] (one wave per row
    // group — the pair holds identical A), then write Uh[b][c][n] 64B-run stores.
    if (z == 1) {
        if (h == 0) {
#pragma unroll
            for (int kc = 0; kc < 8; ++kc) {
                const int c0 = kc * 32 + q4 * 8;
#pragma unroll
                for (int j = 0; j < 8; ++j)
                    S[(c0 + j) * 32 + nloc] = A[kc][j];
            }
        }
        ASYNC_BARRIER();
        {
            _Float16* ub = Uh + (size_t)b * NC * NS + nt2 * 32;
#pragma unroll
            for (int i = 0; i < 4; ++i) {
                const int idx16 = tid + i * 256;         // 1024 x 16B chunks
                const int c = idx16 >> 2, part = idx16 & 3;
                const v8h v = *(const v8h*)(S + idx16 * 8);
                __builtin_nontemporal_store(v, (v8h*)(ub + (size_t)c * NS + part * 8));
            }
        }
        ASYNC_BARRIER();   // S reads retired before the output staging below
    }

#pragma unroll 4
    for (int os2 = 0; os2 < 8; ++os2) {
        const int osub = h * 8 + os2;
        const int o = osub * 16 + l15;
        v4f acc = {0.f, 0.f, 0.f, 0.f};
#pragma unroll
        for (int kc = 0; kc < 8; ++kc) {
            // pre-swizzled W: wave reads 1 KB contiguous, lane-coalesced b128
            const v8h bf = *(const v8h*)(W + ((size_t)(osub * 8 + kc) * 64 + lane) * 8);
            acc = __builtin_amdgcn_mfma_f32_16x16x32_f16(A[kc], bf, acc, 0, 0, 0);
        }
        const float bv = bias[o];
        // stage rows in S[32][256]; q scaled by log2e (base-2 softmax)
#pragma unroll
        for (int r = 0; r < 4; ++r) {
            const float v = z == 0 ? (acc[r] + bv) * LOG2E : (acc[r] + bv);
            S[(g * 16 + q4 * 4 + r) * 256 + o] = (_Float16)v;
        }
    }
    ASYNC_BARRIER();

    if (z == 0) {
        // qT rows nt2*32..+32 are one contiguous 16 KB block
        _Float16* dstQ = qT + ((size_t)b * NS + nt2 * 32) * NC;
#pragma unroll
        for (int i = 0; i < 4; ++i) {
            const int idx16 = tid + i * 256;
            const v8h v = *(const v8h*)(S + idx16 * 8);
            __builtin_nontemporal_store(v, (v8h*)(dstQ + (size_t)idx16 * 8));
        }
    } else {
        // kTsw: this block's 32 rows are exactly tile nt2; 512B runs per row
        _Float16* kb = kTsw + (size_t)b * 128 * KTILE;
#pragma unroll
        for (int i = 0; i < 4; ++i) {
            const int idx16 = tid + i * 256;
            const int row = idx16 >> 5, col = (idx16 & 31) * 8;
            const v8h v = *(const v8h*)(S + idx16 * 8);
            __builtin_nontemporal_store(v,
                (v8h*)(kb + (size_t)nt2 * KTILE + row * KSTRIDE + col));
        }
    }
}

// ---------------- K2: flash attention partial, pipelined single-barrier ----
template <int NSPL>
__global__ __launch_bounds__(256, 3) void k_attn(const _Float16* __restrict__ qT,
    const _Float16* __restrict__ kTsw, const _Float16* __restrict__ Uh,
    _Float16* __restrict__ Ppart, float* __restrict__ mstat, float* __restrict__ lstat)
{
    const int b  = blockIdx.x;
    const int nt = blockIdx.y;
    const int s  = blockIdx.z;
    const int t0 = (s * 128) / NSPL;
    const int t1 = ((s + 1) * 128) / NSPL;

    __shared__ __align__(16) _Float16 Klds[2][KTILE];        // 2 x 17 KiB, padded
    __shared__ __align__(16) _Float16 Plds[2][64 * PSTRIDE]; // 2 x 5 KiB, padded
    __shared__ __align__(16) float alphaS[2][64];

    const int tid = threadIdx.x, w = tid >> 6, lane = tid & 63;
    const int q4 = lane >> 4, l15 = lane & 15;

    const _Float16* kTb = kTsw + (size_t)b * 128 * KTILE;
    const _Float16* Uhb = Uh + (size_t)b * NC * NS;

    v8h Q[8];
    v8h Ur[4];
    v4f O[4][4];
    v4f sv[2];
    float mi[4] = {-INFINITY, -INFINITY, -INFINITY, -INFINITY};
    float li[4] = {0.f, 0.f, 0.f, 0.f};   // lane-local partial (own cols only)

    // DMA one 32-row K tile (17 chunks of 1 KiB; 5 per wave via (w*5+j)%17,
    // chunks 0..2 double-copied -> uniform 5 outstanding per wave)
    auto DMA = [&](int t, int kb) {
        const _Float16* src = kTb + (size_t)t * KTILE;
#pragma unroll
        for (int j = 0; j < 5; ++j) {
            const int ch = (w * 5 + j) % 17;
            __builtin_amdgcn_global_load_lds(
                (const __attribute__((address_space(1))) void*)(src + ch * 512 + lane * 8),
                (__attribute__((address_space(3))) void*)(&Klds[kb][ch * 512]), 16, 0, 0);
        }
    };
    // QK^T from Klds[kb]: 16 n-rows x 32 m per wave
    auto QK = [&](int kb) {
        sv[0] = (v4f){0.f, 0.f, 0.f, 0.f};
        sv[1] = (v4f){0.f, 0.f, 0.f, 0.f};
#pragma unroll
        for (int kc = 0; kc < 8; ++kc) {
#pragma unroll
            for (int ms = 0; ms < 2; ++ms) {
                const v8h kf = *(const v8h*)(&Klds[kb][(ms * 16 + l15) * KSTRIDE
                                             + (kc * 4 + q4) * 8]);
                sv[ms] = __builtin_amdgcn_mfma_f32_16x16x32_f16(Q[kc], kf, sv[ms], 0, 0, 0);
            }
        }
    };
    // online softmax (base-2) on sv, write P/alpha into buffer pb
    auto SMAX = [&](int pb) {
        float al[4];
#pragma unroll
        for (int r = 0; r < 4; ++r) {
            const float tm = row_max16(fmaxf(sv[0][r], sv[1][r]));
            const float mn = fmaxf(mi[r], tm);
            al[r] = __builtin_amdgcn_exp2f(mi[r] - mn);
            mi[r] = mn;
            const float p0 = __builtin_amdgcn_exp2f(sv[0][r] - mn);
            const float p1 = __builtin_amdgcn_exp2f(sv[1][r] - mn);
            sv[0][r] = p0; sv[1][r] = p1;
            li[r] = li[r] * al[r] + p0 + p1;
        }
        if (l15 == 0) {
#pragma unroll
            for (int r = 0; r < 4; ++r) alphaS[pb][w * 16 + q4 * 4 + r] = al[r];
        }
#pragma unroll
        for (int ms = 0; ms < 2; ++ms)
#pragma unroll
            for (int r = 0; r < 4; ++r) {
                const int row = w * 16 + q4 * 4 + r;
                Plds[pb][row * PSTRIDE + ms * 16 + l15] = (_Float16)sv[ms][r];
            }
    };
    // O = O*alpha + P x U, reading buffer pb (written LAST iteration)
    auto PV = [&](int pb) {
#pragma unroll
        for (int is = 0; is < 4; ++is) {
            const float4 av = *(const float4*)&alphaS[pb][is * 16 + q4 * 4];
            const v4f aa = {av.x, av.y, av.z, av.w};
#pragma unroll
            for (int js = 0; js < 4; ++js) O[is][js] *= aa;
        }
#pragma unroll
        for (int is = 0; is < 4; ++is) {
            const v8h Pf = *(const v8h*)(&Plds[pb][(is * 16 + l15) * PSTRIDE + q4 * 8]);
#pragma unroll
            for (int js = 0; js < 4; ++js)
                O[is][js] = __builtin_amdgcn_mfma_f32_16x16x32_f16(Pf, Ur[js], O[is][js], 0, 0, 0);
        }
    };
    auto ULOAD = [&](int t) {
#pragma unroll
        for (int js = 0; js < 4; ++js)
            Ur[js] = *(const v8h*)(Uhb + (size_t)(w * 64 + js * 16 + l15) * NS
                                   + t * 32 + q4 * 8);
    };

#pragma unroll
    for (int i = 0; i < 4; ++i)
#pragma unroll
        for (int j = 0; j < 4; ++j) O[i][j] = (v4f){0.f, 0.f, 0.f, 0.f};

    // ---- prologue: DMA K[t0]; Q; QK(t0); DMA K[t0+1]; softmax(t0); U[t0] ----
    DMA(t0, 0);
    asm volatile("" ::: "memory");
    {
        const _Float16* qrow = qT + ((size_t)b * NS + nt * 64 + w * 16 + l15) * NC;
#pragma unroll
        for (int kc = 0; kc < 8; ++kc) Q[kc] = *(const v8h*)(qrow + kc * 32 + q4 * 8);
    }
    asm volatile("" ::: "memory");
    asm volatile("s_waitcnt vmcnt(8)" ::: "memory");   // retire DMA(t0), keep Q(8)
    ASYNC_BARRIER();                                    // K[t0] resident
    QK(0);
    DMA((t0 + 1 < t1) ? t0 + 1 : t0, 1);
    asm volatile("" ::: "memory");
    SMAX(0);
    ULOAD(t0);

    // ---- main loop: one barrier per tile; PV(t-1) overlaps softmax(t) ----
    for (int t = t0 + 1; t < t1; ++t) {
        const int e = (t - t0) & 1;
        // outstanding: DMA(t)=5 oldest, U(t-1)=4 -> retire DMA(t) only
        asm volatile("s_waitcnt vmcnt(4)" ::: "memory");
        ASYNC_BARRIER();   // K[t] resident; P/alpha[e^1] visible; p^1-reads retired
        QK(e);
        DMA((t + 1 < t1) ? t + 1 : t0, e ^ 1);          // post-barrier issue (safe)
        asm volatile("" ::: "memory");
        PV(e ^ 1);         // MFMA pipe: finish tile t-1
        SMAX(e);           // VALU pipe: softmax tile t (other blocks' MFMA overlaps)
        ULOAD(t);          // U[t] for PV(t) next iter (old Ur just consumed)
    }

    // ---- epilogue: finish PV(t1-1); drain wrap DMA ----
    asm volatile("s_waitcnt vmcnt(0)" ::: "memory");
    ASYNC_BARRIER();       // Plds/alphaS of last tile visible
    PV((t1 - 1 - t0) & 1);

    // reduce li across the quad-row, write stats + raw O
#pragma unroll
    for (int r = 0; r < 4; ++r) li[r] = row_sum16(li[r]);
    if (l15 == 0) {
#pragma unroll
        for (int r = 0; r < 4; ++r) {
            const int n = nt * 64 + w * 16 + q4 * 4 + r;
            mstat[(size_t)(s * NB + b) * NS + n] = mi[r];
            lstat[(size_t)(s * NB + b) * NS + n] = li[r];
        }
    }
#pragma unroll
    for (int is = 0; is < 4; ++is)
#pragma unroll
        for (int js = 0; js < 4; ++js)
#pragma unroll
            for (int r = 0; r < 4; ++r) {
                _Float16* dst = Ppart + ((size_t)(s * NB + b) * NS + nt * 64 + is * 16
                                         + q4 * 4 + r) * NC + w * 64 + js * 16 + l15;
                __builtin_nontemporal_store((_Float16)O[is][js][r], dst);
            }
}

// ---------------- K3: merge NSPL partials -> fp16 Opre + fused GN sums -----
// exp2 domain; statacc is NSLOT-slot [slot][b][g][2] to spread atomic contention.
// Opre now fp16 (merged O already fp16-rounded via Ppart; stats from fp32 v).
template <int NSPL>
__global__ __launch_bounds__(256) void k_merge(const _Float16* __restrict__ Pp,
    const float* __restrict__ mstat, const float* __restrict__ lstat,
    _Float16* __restrict__ Opre, float* __restrict__ statacc)
{
    const int b = blockIdx.y, tid = threadIdx.x;
    const int n = blockIdx.x * 8 + (tid >> 5);
    const int slot = blockIdx.x & (NSLOT - 1);
    const int c0 = (tid & 31) * 8;            // == group (tid&31) exactly
    const size_t nb = (size_t)b * NS + n;
    const size_t SP = (size_t)NB * NS;

    float m[NSPL], l[NSPL];
#pragma unroll
    for (int sp = 0; sp < NSPL; ++sp) {
        m[sp] = mstat[sp * SP + nb];
        l[sp] = lstat[sp * SP + nb];
    }
    float M = m[0];
#pragma unroll
    for (int sp = 1; sp < NSPL; ++sp) M = fmaxf(M, m[sp]);
    float denom = 0.f, wgt[NSPL];
#pragma unroll
    for (int sp = 0; sp < NSPL; ++sp) {
        wgt[sp] = exp2f(m[sp] - M);
        denom += wgt[sp] * l[sp];
    }
    const float inv = 1.f / denom;

    const size_t base = nb * NC + c0;
    float v[8] = {0.f, 0.f, 0.f, 0.f, 0.f, 0.f, 0.f, 0.f};
#pragma unroll
    for (int sp = 0; sp < NSPL; ++sp) {
        const float ws = wgt[sp] * inv;
        const v8h pv = *(const v8h*)(Pp + (size_t)sp * SP * NC + base);
#pragma unroll
        for (int j = 0; j < 8; ++j) v[j] += ws * (float)pv[j];
    }
    float s1 = 0.f, s2 = 0.f;
    v8h o16;
#pragma unroll
    for (int j = 0; j < 8; ++j) {
        s1 += v[j]; s2 += v[j] * v[j];
        o16[j] = (_Float16)v[j];
    }
    *(v8h*)(Opre + base) = o16;

    __shared__ float r1[256], r2[256];
    r1[tid] = s1; r2[tid] = s2;
    __syncthreads();
    if (tid < 32) {
        float a = 0.f, q = 0.f;
#pragma unroll
        for (int k = 0; k < 8; ++k) { a += r1[tid + 32 * k]; q += r2[tid + 32 * k]; }
        atomicAdd(&statacc[(((size_t)slot * NB + b) * NG + tid) * 2 + 0], a);
        atomicAdd(&statacc[(((size_t)slot * NB + b) * NG + tid) * 2 + 1], q);
    }
}

// ---------------- K4: apply GN + residual, [b][n][c] -> [b][c][n] ----------
__global__ __launch_bounds__(256) void k_gnapply(const _Float16* __restrict__ Opre,
    const float* __restrict__ Hand, const float* __restrict__ gnw,
    const float* __restrict__ gnb, const float* __restrict__ statacc,
    float* __restrict__ out)
{
    const int nt = blockIdx.x, ct = blockIdx.y, b = blockIdx.z;
    __shared__ float buf[64 * 65];
    __shared__ float gstat[16];   // 8 local groups x {sum, sumsq}
    const int tid = threadIdx.x;
    // pre-reduce the NSLOT statacc slots for this block's 8 channel-groups
    if (tid < 16) {
        const int gl = tid >> 1, comp = tid & 1;
        const int g = ct * 8 + gl;
        float s = 0.f;
#pragma unroll
        for (int sl = 0; sl < NSLOT; ++sl)
            s += statacc[(((size_t)sl * NB + b) * NG + g) * 2 + comp];
        gstat[gl * 2 + comp] = s;
    }
    {
        // 64 n x 64 ch as 512 v8h chunks; 2 per thread
#pragma unroll
        for (int i = 0; i < 2; ++i) {
            const int idx = tid + i * 256;
            const int n = idx >> 3, g8 = (idx & 7) * 8;
            const v8h v = *(const v8h*)(Opre + ((size_t)b * NS + nt * 64 + n) * NC
                                        + ct * 64 + g8);
#pragma unroll
            for (int j = 0; j < 8; ++j) buf[n * 65 + g8 + j] = (float)v[j];
        }
    }
    __syncthreads();
    const int nw = tid & 63, c0 = tid >> 6;
#pragma unroll
    for (int k = 0; k < 16; ++k) {
        const int cl = c0 + 4 * k;
        const int c  = ct * 64 + cl;
        const int gl = cl >> 3;
        const float s1   = gstat[gl * 2 + 0];
        const float s2   = gstat[gl * 2 + 1];
        const float mean = s1 * (1.f / 32768.f);
        const float var  = s2 * (1.f / 32768.f) - mean * mean;
        const float rstd = rsqrtf(var + GEPS);
        const size_t oidx = ((size_t)b * NC + c) * NS + nt * 64 + nw;
        out[oidx] = (buf[nw * 65 + cl] - mean) * rstd * gnw[c] + gnb[c] + Hand[oidx];
    }
}

extern "C" void kernel_launch(void* const* d_in, const int* in_sizes, int n_in,
                              void* d_out, int out_size, void* d_ws, size_t ws_size,
                              hipStream_t stream)
{
    const float* Hand = (const float*)d_in[0];
    const float* U    = (const float*)d_in[1];
    const float* WHw  = (const float*)d_in[2];
    const float* WHb  = (const float*)d_in[3];
    const float* WUw  = (const float*)d_in[4];
    const float* WUb  = (const float*)d_in[5];
    const float* gnw  = (const float*)d_in[6];
    const float* gnb  = (const float*)d_in[7];
    float* out = (float*)d_out;

    // workspace (~49.2 MiB). Opre (fp16, 8Mi) ALIASES qT (dead post-attn).
    char* ws = (char*)d_ws;
    _Float16* qT     = (_Float16*)(ws);                  //  8 MiB   [b][n][c]
    _Float16* kTsw   = (_Float16*)(ws + 8388608);        //  8.5 MiB padded 32-row tiles
    _Float16* Uh     = (_Float16*)(ws + 17301504);       //  8 MiB   [b][c][m]
    _Float16* Wh16   = (_Float16*)(ws + 25690112);       //  128 KiB (frag-order)
    _Float16* Wu16   = (_Float16*)(ws + 25821184);       //  128 KiB (frag-order)
    float*    mstat  = (float*)(ws + 25952256);          //  192 KiB [3][b][n]
    float*    lstat  = (float*)(ws + 26148864);          //  192 KiB
    float*    statacc= (float*)(ws + 26345472);          //  16 KiB [slot][b][g][2]
    _Float16* Ppart  = (_Float16*)(ws + 26361856);       //  24 MiB [3][b][n][c]
    _Float16* Opre   = (_Float16*)(ws);                  //  8 MiB alias (qT dead)

    k_convert<<<dim3((NC * NC) / 256), 256, 0, stream>>>(WHw, WUw, Wh16, Wu16, statacc);
    k_qkgemm <<<dim3(128, NB, 2), 256, 0, stream>>>(Hand, U, Wh16, Wu16, WHb, WUb, qT, kTsw, Uh);
    k_attn<NSPLIT>   <<<dim3(NB, 64, NSPLIT), 256, 0, stream>>>(qT, kTsw, Uh, Ppart, mstat, lstat);
    k_merge<NSPLIT>  <<<dim3(NS / 8, NB), 256, 0, stream>>>(Ppart, mstat, lstat, Opre, statacc);
    k_gnapply<<<dim3(64, 4, NB), 256, 0, stream>>>(Opre, Hand, gnw, gnb, statacc, out);
}